// Round 2
// baseline (88.101 us; speedup 1.0000x reference)
//
#include <hip/hip_runtime.h>
#include <math.h>

#define IN_DIM 512
#define NC 100
#define NCP 128
#define NN 63
#define NE 16
#define NL 64
#define BATCH 8192
#define KDIM 1024

typedef float F8 __attribute__((ext_vector_type(8)));

// ---------------- Kernel A: per-node argmax/max over IN_DIM ----------------
__global__ __launch_bounds__(64) void node_argmax_kernel(
    const float* __restrict__ T, float* __restrict__ tmax, int* __restrict__ dstar) {
  const int node = blockIdx.x;  // 0..1007 == e*63+n
  const float4* row = reinterpret_cast<const float4*>(T + (size_t)node * IN_DIM);
  const int lane = threadIdx.x;
  float best = -INFINITY;
  int bidx = 0;
#pragma unroll
  for (int i = 0; i < 2; ++i) {
    const int f4 = lane + 64 * i;
    const float4 v = row[f4];
    const int base = f4 * 4;
    if (v.x > best) { best = v.x; bidx = base; }
    if (v.y > best) { best = v.y; bidx = base + 1; }
    if (v.z > best) { best = v.z; bidx = base + 2; }
    if (v.w > best) { best = v.w; bidx = base + 3; }
  }
#pragma unroll
  for (int off = 32; off; off >>= 1) {
    const float ov = __shfl_xor(best, off);
    const int oi = __shfl_xor(bidx, off);
    if (ov > best || (ov == best && oi < bidx)) { best = ov; bidx = oi; }
  }
  if (lane == 0) {
    tmax[node] = best;
    dstar[node] = bidx;
  }
}

// ---------------- Kernel X: transpose x (8192x512) -> xT (512x8192) ----------------
__global__ __launch_bounds__(256) void xt_kernel(const float* __restrict__ x,
                                                 float* __restrict__ xT) {
  __shared__ float t[64][65];
  const int b0 = (blockIdx.x >> 3) * 64;  // 128 batch tiles
  const int d0 = (blockIdx.x & 7) * 64;   // 8 feature tiles
  const int r = threadIdx.x >> 2;
  const int q = threadIdx.x & 3;
  const float* src = x + (size_t)(b0 + r) * IN_DIM + d0 + q * 16;
#pragma unroll
  for (int i = 0; i < 4; ++i) {
    const float4 v = *reinterpret_cast<const float4*>(src + i * 4);
    t[r][q * 16 + i * 4 + 0] = v.x;
    t[r][q * 16 + i * 4 + 1] = v.y;
    t[r][q * 16 + i * 4 + 2] = v.z;
    t[r][q * 16 + i * 4 + 3] = v.w;
  }
  __syncthreads();
  float* dst = xT + (size_t)(d0 + r) * BATCH + b0 + q * 16;
#pragma unroll
  for (int i = 0; i < 4; ++i) {
    float4 v;
    v.x = t[q * 16 + i * 4 + 0][r];
    v.y = t[q * 16 + i * 4 + 1][r];
    v.z = t[q * 16 + i * 4 + 2][r];
    v.w = t[q * 16 + i * 4 + 3][r];
    *reinterpret_cast<float4*>(dst + i * 4) = v;
  }
}

// ---------------- Kernel LT: L (1024,100) -> LTi[kc][c][j] padded to 128 classes ----
__global__ __launch_bounds__(256) void lt_kernel(const float* __restrict__ L,
                                                 float* __restrict__ LTi) {
  const int i = blockIdx.x * 256 + threadIdx.x;  // 256*128*4 = 131072
  const int j = i & 3;
  const int c = (i >> 2) & 127;
  const int kc = i >> 9;
  const int k = kc * 4 + j;
  LTi[i] = (c < NC) ? L[(size_t)k * NC + c] : 0.0f;
}

// ---------------- Kernel P: tree products -> Pt[k][b] (k-major, 1024 x 8192) --------
__global__ __launch_bounds__(256) void p_kernel(const float* __restrict__ xT,
                                                const float* __restrict__ tmax,
                                                const int* __restrict__ dstar,
                                                float* __restrict__ Pt) {
  __shared__ float s[NN][68];
  const int rtile = blockIdx.x >> 4;
  const int e = blockIdx.x & 15;
  const int b0 = rtile * 64;
  const int tid = threadIdx.x;

  // phase A: s[n][r] = floor(tmax[e,n] - x[b0+r][dstar[e,n]])   (coalesced via xT)
  for (int i = tid; i < NN * 64; i += 256) {
    const int n = i >> 6;
    const int r = i & 63;
    const float tv = tmax[e * NN + n];
    const int dv = dstar[e * NN + n];
    s[n][r] = floorf(tv - xT[(size_t)dv * BATCH + b0 + r]);
  }
  __syncthreads();

  // phase B: each thread: row r, leaf group lg (16 leaves)
  const int r = tid & 63;
  const int lg = tid >> 6;  // 0..3
  const float s1 = s[0][r];
  const float s2 = s[1 + (lg >> 1)][r];
  const float s3 = s[3 + lg][r];
  const float f1 = ((lg >> 1) & 1) ? 1.0f - s1 : s1;
  const float f2 = (lg & 1) ? 1.0f - s2 : s2;
  const float stem = f1 * f2;
  const float c3a = stem * s3;            // bit3 = 0 (i<8)
  const float c3b = stem * (1.0f - s3);   // bit3 = 1 (i>=8)
  const float s4a = s[7 + 2 * lg][r];
  const float s4b = s[8 + 2 * lg][r];
  float c5in[4];
  c5in[0] = c3a * s4a;            // q=0: h=0,b4=0
  c5in[1] = c3a * (1.0f - s4a);   // q=1: h=0,b4=1
  c5in[2] = c3b * s4b;            // q=2: h=1,b4=0
  c5in[3] = c3b * (1.0f - s4b);   // q=3: h=1,b4=1
  float p[16];
#pragma unroll
  for (int q = 0; q < 4; ++q) {
    const float s5 = s[15 + 4 * lg + q][r];
    const float a = c5in[q] * s5;
    const float b = c5in[q] * (1.0f - s5);
#pragma unroll
    for (int b5 = 0; b5 < 2; ++b5) {
      const int m = 2 * q + b5;
      const float s6 = s[31 + 8 * lg + m][r];
      const float base = b5 ? b : a;
      p[m * 2 + 0] = base * s6;
      p[m * 2 + 1] = base * (1.0f - s6);
    }
  }
  float* dst = Pt + (size_t)(e * 64 + lg * 16) * BATCH + b0 + r;
#pragma unroll
  for (int i = 0; i < 16; ++i) dst[(size_t)i * BATCH] = p[i];
}

// ---------------- Kernel G: y_part = Pt^T @ LTi  (SGPR-broadcast p, zero LDS) -------
__global__ __launch_bounds__(256) void gemm_kernel(const float* __restrict__ Pt,
                                                   const float* __restrict__ LTi,
                                                   float* __restrict__ yws) {
  const int bid = blockIdx.x;       // 1024 = 512 row-tiles x 2 k-halves
  const int rt = bid >> 1;
  const int eh = bid & 1;
  const int tid = threadIdx.x;
  const int w = tid >> 6;
  const int lane = tid & 63;
  const int c = (w & 1) * 64 + lane;        // class 0..127
  const int b0 = rt * 16 + (w >> 1) * 8;    // 8 rows per wave, wave-uniform
  const int b0s = __builtin_amdgcn_readfirstlane(b0);

  float acc[8];
#pragma unroll
  for (int j = 0; j < 8; ++j) acc[j] = 0.0f;

  const float* lbase = LTi + c * 4;
  const float* pbase = Pt + (size_t)(eh * 512) * BATCH + b0s;
  const int k0 = eh * 512;
#pragma unroll 2
  for (int kk = 0; kk < 512; kk += 4) {
    const F8 p0 = *reinterpret_cast<const F8*>(pbase + (size_t)0 * BATCH);
    const F8 p1 = *reinterpret_cast<const F8*>(pbase + (size_t)1 * BATCH);
    const F8 p2 = *reinterpret_cast<const F8*>(pbase + (size_t)2 * BATCH);
    const F8 p3 = *reinterpret_cast<const F8*>(pbase + (size_t)3 * BATCH);
    const float4 lv = *reinterpret_cast<const float4*>(lbase + (size_t)((k0 + kk) >> 2) * 512);
#pragma unroll
    for (int j = 0; j < 8; ++j) {
      float a = acc[j];
      a = fmaf(p0[j], lv.x, a);
      a = fmaf(p1[j], lv.y, a);
      a = fmaf(p2[j], lv.z, a);
      a = fmaf(p3[j], lv.w, a);
      acc[j] = a;
    }
    pbase += (size_t)4 * BATCH;
  }
  float* o = yws + ((size_t)eh * BATCH + b0) * NCP + c;
#pragma unroll
  for (int j = 0; j < 8; ++j) o[(size_t)j * NCP] = acc[j];
}

// ---------------- Kernel S: combine k-halves + masked softmax ----------------
__global__ __launch_bounds__(256) void sm_kernel(const float* __restrict__ yws,
                                                 float* __restrict__ out) {
  const int r = blockIdx.x * 4 + (threadIdx.x >> 6);
  const int lane = threadIdx.x & 63;
  const float* y0 = yws + (size_t)r * NCP;
  const float* y1 = yws + (size_t)(BATCH + r) * NCP;
  const float v1 = y0[lane] + y1[lane];
  const float v2 = (lane + 64 < NC) ? (y0[lane + 64] + y1[lane + 64]) : -INFINITY;
  float m = fmaxf(v1, v2);
#pragma unroll
  for (int off = 32; off; off >>= 1) m = fmaxf(m, __shfl_xor(m, off));
  const float e1 = __expf(v1 - m);
  const float e2 = (lane + 64 < NC) ? __expf(v2 - m) : 0.0f;
  float ss = e1 + e2;
#pragma unroll
  for (int off = 32; off; off >>= 1) ss += __shfl_xor(ss, off);
  const float inv = 1.0f / ss;
  float* orow = out + (size_t)r * NC;
  orow[lane] = e1 * inv;
  if (lane + 64 < NC) orow[lane + 64] = e2 * inv;
}

extern "C" void kernel_launch(void* const* d_in, const int* in_sizes, int n_in,
                              void* d_out, int out_size, void* d_ws, size_t ws_size,
                              hipStream_t stream) {
  const float* x = (const float*)d_in[0];  // (8192, 512)
  const float* T = (const float*)d_in[1];  // (16, 63, 512)
  const float* L = (const float*)d_in[2];  // (16, 64, 100)
  float* out = (float*)d_out;              // (8192, 100)

  float* ws = (float*)d_ws;
  // float-offset layout (total ~56.5 MB)
  float* Pt   = ws;                         // 1024*8192
  float* xT   = ws + 8388608;               // 512*8192
  float* yws  = ws + 12582912;              // 2*8192*128
  float* LTi  = ws + 14680064;              // 256*128*4
  float* tmax = ws + 14811136;              // 1008
  int*   dst  = (int*)(ws + 14812144);      // 1008

  node_argmax_kernel<<<NE * NN, 64, 0, stream>>>(T, tmax, dst);
  xt_kernel<<<1024, 256, 0, stream>>>(x, xT);
  lt_kernel<<<512, 256, 0, stream>>>(L, LTi);
  p_kernel<<<2048, 256, 0, stream>>>(xT, tmax, dst, Pt);
  gemm_kernel<<<1024, 256, 0, stream>>>(Pt, LTi, yws);
  sm_kernel<<<2048, 256, 0, stream>>>(yws, out);
}

// Round 3
// 64.514 us; speedup vs baseline: 1.3656x; 1.3656x over previous
//
#include <hip/hip_runtime.h>
#include <hip/hip_bf16.h>
#include <math.h>

#define IN_DIM 512
#define NC 100
#define NN 63
#define NE 16
#define BATCH 8192
#define XP 516   // padded x row stride (floats); keeps float4 alignment, 2-way-max gather conflicts

typedef __attribute__((ext_vector_type(8))) short bf16x8;
typedef __attribute__((ext_vector_type(4))) float f32x4;

static __device__ __forceinline__ ushort bf16_bits(__hip_bfloat16 h) {
  union { __hip_bfloat16 b; ushort u; } cv; cv.b = h; return cv.u;
}

// ---------------- Kernel A: per-node argmax/max over IN_DIM ----------------
__global__ __launch_bounds__(64) void node_argmax_kernel(
    const float* __restrict__ T, float* __restrict__ tmax, int* __restrict__ dstar) {
  const int node = blockIdx.x;  // 0..1007 == e*63+n
  const float4* row = reinterpret_cast<const float4*>(T + (size_t)node * IN_DIM);
  const int lane = threadIdx.x;
  float best = -INFINITY;
  int bidx = 0;
#pragma unroll
  for (int i = 0; i < 2; ++i) {
    const int f4 = lane + 64 * i;
    const float4 v = row[f4];
    const int base = f4 * 4;
    if (v.x > best) { best = v.x; bidx = base; }
    if (v.y > best) { best = v.y; bidx = base + 1; }
    if (v.z > best) { best = v.z; bidx = base + 2; }
    if (v.w > best) { best = v.w; bidx = base + 3; }
  }
#pragma unroll
  for (int off = 32; off; off >>= 1) {
    const float ov = __shfl_xor(best, off);
    const int oi = __shfl_xor(bidx, off);
    if (ov > best || (ov == best && oi < bidx)) { best = ov; bidx = oi; }
  }
  if (lane == 0) {
    tmax[node] = best;
    dstar[node] = bidx;
  }
}

// ---------------- Kernel LT: L -> B-fragments [kc][hl][cf][lane][8] bf16 hi/lo ------
__global__ __launch_bounds__(256) void lt_frag_kernel(const float* __restrict__ L,
                                                      ushort* __restrict__ Bfrag) {
  const int i = blockIdx.x * 256 + threadIdx.x;  // 262144 elements
  const int j = i & 7;
  const int lane = (i >> 3) & 63;
  const int cf = (i >> 9) & 7;
  const int hl = (i >> 12) & 1;
  const int kc = i >> 13;
  const int k = kc * 32 + (lane >> 4) * 8 + j;
  const int c = cf * 16 + (lane & 15);
  const float val = (c < NC) ? L[(size_t)k * NC + c] : 0.0f;
  const __hip_bfloat16 hb = __float2bfloat16(val);
  ushort outv;
  if (hl == 0) {
    outv = bf16_bits(hb);
  } else {
    const __hip_bfloat16 lb = __float2bfloat16(val - __bfloat162float(hb));
    outv = bf16_bits(lb);
  }
  Bfrag[i] = outv;
}

// ---------------- Kernel P: x-stage + tree products -> A-fragments ------------------
// Pfrag layout: [rt(512)][kc(32)][hl(2)][lane(64)][j(8)] bf16  (rt = 16-row tile)
__global__ __launch_bounds__(256) void p_frag_kernel(const float* __restrict__ x,
                                                     const float* __restrict__ tmaxg,
                                                     const int* __restrict__ dstarg,
                                                     ushort* __restrict__ Pfrag) {
  __shared__ __align__(16) float xl[16 * XP];  // 33 KB
  __shared__ float tl[NE * NN];
  __shared__ int dl[NE * NN];
  const int tid = threadIdx.x;
  const int rt = blockIdx.x;
  const int b0 = rt * 16;

  // stage 16 x rows, coalesced float4
  {
    const float4* xg = reinterpret_cast<const float4*>(x + (size_t)b0 * IN_DIM);
#pragma unroll
    for (int i = 0; i < 8; ++i) {
      const int idx = tid + i * 256;   // 0..2047
      const int r = idx >> 7;          // 128 float4 per row
      const int c4 = idx & 127;
      *reinterpret_cast<float4*>(&xl[r * XP + c4 * 4]) = xg[r * 128 + c4];
    }
    for (int i = tid; i < NE * NN; i += 256) { tl[i] = tmaxg[i]; dl[i] = dstarg[i]; }
  }
  __syncthreads();

  const int r = tid & 15;
  const int lg = (tid >> 4) & 7;
  const int eo = tid >> 7;
  const float* xr = &xl[r * XP];
  const int lane = r + 16 * (lg & 3);

  for (int rnd = 0; rnd < 8; ++rnd) {
    const int e = rnd * 2 + eo;
    const float* te = &tl[e * NN];
    const int* de = &dl[e * NN];
    // s-values along the 8 leaves' shared paths
    const float s1 = floorf(te[0] - xr[de[0]]);
    const int n2 = 1 + (lg >> 2), n3 = 3 + (lg >> 1), n4 = 7 + lg;
    const float s2 = floorf(te[n2] - xr[de[n2]]);
    const float s3 = floorf(te[n3] - xr[de[n3]]);
    const float s4 = floorf(te[n4] - xr[de[n4]]);
    const int n5 = 15 + 2 * lg, n6 = 31 + 4 * lg;
    const float s5a = floorf(te[n5] - xr[de[n5]]);
    const float s5b = floorf(te[n5 + 1] - xr[de[n5 + 1]]);
    const float s60 = floorf(te[n6] - xr[de[n6]]);
    const float s61 = floorf(te[n6 + 1] - xr[de[n6 + 1]]);
    const float s62 = floorf(te[n6 + 2] - xr[de[n6 + 2]]);
    const float s63 = floorf(te[n6 + 3] - xr[de[n6 + 3]]);

    const float f1 = ((lg >> 2) & 1) ? 1.0f - s1 : s1;
    const float f2 = ((lg >> 1) & 1) ? 1.0f - s2 : s2;
    const float f3 = (lg & 1) ? 1.0f - s3 : s3;
    const float stem = f1 * f2 * f3;
    const float qa = stem * s4, qb = stem * (1.0f - s4);
    const float w00 = qa * s5a, w01 = qa * (1.0f - s5a);
    const float w10 = qb * s5b, w11 = qb * (1.0f - s5b);
    float p[8];
    p[0] = w00 * s60; p[1] = w00 * (1.0f - s60);
    p[2] = w01 * s61; p[3] = w01 * (1.0f - s61);
    p[4] = w10 * s62; p[5] = w10 * (1.0f - s62);
    p[6] = w11 * s63; p[7] = w11 * (1.0f - s63);

    union { ushort u[8]; float4 v; } H, Lo;
#pragma unroll
    for (int i2 = 0; i2 < 8; ++i2) {
      const __hip_bfloat16 hb = __float2bfloat16(p[i2]);
      const float hf = __bfloat162float(hb);
      const __hip_bfloat16 lb = __float2bfloat16(p[i2] - hf);
      H.u[i2] = bf16_bits(hb);
      Lo.u[i2] = bf16_bits(lb);
    }
    const int kc = e * 2 + (lg >> 2);
    ushort* dsth = Pfrag + ((((size_t)rt * 32 + kc) * 2 + 0) * 64 + lane) * 8;
    ushort* dstl = Pfrag + ((((size_t)rt * 32 + kc) * 2 + 1) * 64 + lane) * 8;
    *reinterpret_cast<float4*>(dsth) = H.v;
    *reinterpret_cast<float4*>(dstl) = Lo.v;
  }
}

// ---------------- Kernel G: MFMA GEMM, 128 rows x 128 cols per block, ksplit=4 ------
__global__ __launch_bounds__(256) void gemm_mfma_kernel(const ushort* __restrict__ Pfrag,
                                                        const ushort* __restrict__ Bfrag,
                                                        float* __restrict__ yws) {
  __shared__ __align__(16) ushort LB[2][16 * 512];  // [buf][hl*8cf*64lane*8j] = 16 KB each
  const int tid = threadIdx.x;
  const int bid = blockIdx.x;
  const int rtile = bid >> 2;  // 0..63: 128-row tile
  const int ks = bid & 3;      // 4-way k-split (4 estimators each)
  const int w = tid >> 6, lane = tid & 63;

  f32x4 acc[2][8];
#pragma unroll
  for (int a = 0; a < 2; ++a)
#pragma unroll
    for (int b = 0; b < 8; ++b) acc[a][b] = (f32x4)0.0f;

  const int rt0 = rtile * 8 + w * 2;  // wave's first 16-row tile
  int kcg = ks * 8;

  // stage B fragments for kchunk kcg into LB[buf]: 16 KB, 4 float4/thread
  const float4* bsrc0 = reinterpret_cast<const float4*>(Bfrag);
  {
    const float4* src = bsrc0 + (size_t)kcg * 1024;
    float4* dst = reinterpret_cast<float4*>(LB[0]);
#pragma unroll
    for (int i = 0; i < 4; ++i) dst[tid + 256 * i] = src[tid + 256 * i];
  }

  const bf16x8* ap = reinterpret_cast<const bf16x8*>(Pfrag);
  bf16x8 Ah0 = ap[(((size_t)(rt0 + 0) * 32 + kcg) * 2 + 0) * 64 + lane];
  bf16x8 Al0 = ap[(((size_t)(rt0 + 0) * 32 + kcg) * 2 + 1) * 64 + lane];
  bf16x8 Ah1 = ap[(((size_t)(rt0 + 1) * 32 + kcg) * 2 + 0) * 64 + lane];
  bf16x8 Al1 = ap[(((size_t)(rt0 + 1) * 32 + kcg) * 2 + 1) * 64 + lane];

  for (int kc = 0; kc < 8; ++kc) {
    __syncthreads();  // LB[kc&1] ready
    const int buf = kc & 1;
    if (kc < 7) {  // prefetch next B into other buffer
      const float4* src = bsrc0 + (size_t)(kcg + 1) * 1024;
      float4* dst = reinterpret_cast<float4*>(LB[buf ^ 1]);
#pragma unroll
      for (int i = 0; i < 4; ++i) dst[tid + 256 * i] = src[tid + 256 * i];
    }
    const bf16x8 ah0 = Ah0, al0 = Al0, ah1 = Ah1, al1 = Al1;
    if (kc < 7) {  // prefetch next A fragments
      const int kn = kcg + 1;
      Ah0 = ap[(((size_t)(rt0 + 0) * 32 + kn) * 2 + 0) * 64 + lane];
      Al0 = ap[(((size_t)(rt0 + 0) * 32 + kn) * 2 + 1) * 64 + lane];
      Ah1 = ap[(((size_t)(rt0 + 1) * 32 + kn) * 2 + 0) * 64 + lane];
      Al1 = ap[(((size_t)(rt0 + 1) * 32 + kn) * 2 + 1) * 64 + lane];
    }
    const bf16x8* lb = reinterpret_cast<const bf16x8*>(LB[buf]);
#pragma unroll
    for (int cf = 0; cf < 8; ++cf) {
      const bf16x8 bh = lb[(0 * 8 + cf) * 64 + lane];
      const bf16x8 bl = lb[(1 * 8 + cf) * 64 + lane];
      acc[0][cf] = __builtin_amdgcn_mfma_f32_16x16x32_bf16(ah0, bh, acc[0][cf], 0, 0, 0);
      acc[0][cf] = __builtin_amdgcn_mfma_f32_16x16x32_bf16(al0, bh, acc[0][cf], 0, 0, 0);
      acc[0][cf] = __builtin_amdgcn_mfma_f32_16x16x32_bf16(ah0, bl, acc[0][cf], 0, 0, 0);
      acc[0][cf] = __builtin_amdgcn_mfma_f32_16x16x32_bf16(al0, bl, acc[0][cf], 0, 0, 0);
      acc[1][cf] = __builtin_amdgcn_mfma_f32_16x16x32_bf16(ah1, bh, acc[1][cf], 0, 0, 0);
      acc[1][cf] = __builtin_amdgcn_mfma_f32_16x16x32_bf16(al1, bh, acc[1][cf], 0, 0, 0);
      acc[1][cf] = __builtin_amdgcn_mfma_f32_16x16x32_bf16(ah1, bl, acc[1][cf], 0, 0, 0);
      acc[1][cf] = __builtin_amdgcn_mfma_f32_16x16x32_bf16(al1, bl, acc[1][cf], 0, 0, 0);
    }
    ++kcg;
  }

  // epilogue: partial sums -> yws[ks][row][c]  (C/D: col=lane&15, row=(lane>>4)*4+reg)
  float* yb = yws + (size_t)ks * BATCH * 128;
  const int row0 = rtile * 128 + w * 32;
  const int rlo = (lane >> 4) * 4;
  const int cl = lane & 15;
#pragma unroll
  for (int a = 0; a < 2; ++a)
#pragma unroll
    for (int cf = 0; cf < 8; ++cf)
#pragma unroll
      for (int jj = 0; jj < 4; ++jj) {
        const int rr = row0 + a * 16 + rlo + jj;
        yb[(size_t)rr * 128 + cf * 16 + cl] = acc[a][cf][jj];
      }
}

// ---------------- Kernel S: combine 4 k-partials + masked softmax ----------------
__global__ __launch_bounds__(256) void sm_kernel(const float* __restrict__ yws,
                                                 float* __restrict__ out) {
  const int r = blockIdx.x * 4 + (threadIdx.x >> 6);
  const int lane = threadIdx.x & 63;
  const float* y0 = yws + (size_t)r * 128;
  float v1 = 0.0f, v2 = 0.0f;
#pragma unroll
  for (int s = 0; s < 4; ++s) {
    v1 += y0[(size_t)s * BATCH * 128 + lane];
    v2 += y0[(size_t)s * BATCH * 128 + lane + 64];
  }
  if (lane + 64 >= NC) v2 = -INFINITY;
  float m = fmaxf(v1, v2);
#pragma unroll
  for (int off = 32; off; off >>= 1) m = fmaxf(m, __shfl_xor(m, off));
  const float e1 = __expf(v1 - m);
  const float e2 = (lane + 64 < NC) ? __expf(v2 - m) : 0.0f;
  float ss = e1 + e2;
#pragma unroll
  for (int off = 32; off; off >>= 1) ss += __shfl_xor(ss, off);
  const float inv = 1.0f / ss;
  float* orow = out + (size_t)r * NC;
  orow[lane] = e1 * inv;
  if (lane + 64 < NC) orow[lane + 64] = e2 * inv;
}

extern "C" void kernel_launch(void* const* d_in, const int* in_sizes, int n_in,
                              void* d_out, int out_size, void* d_ws, size_t ws_size,
                              hipStream_t stream) {
  const float* x = (const float*)d_in[0];  // (8192, 512)
  const float* T = (const float*)d_in[1];  // (16, 63, 512)
  const float* L = (const float*)d_in[2];  // (16, 64, 100)
  float* out = (float*)d_out;              // (8192, 100)

  char* ws = (char*)d_ws;
  ushort* Pfrag = (ushort*)ws;                          // 512*32*2*64*8 bf16 = 33,554,432 B
  ushort* Bfrag = (ushort*)(ws + 33554432);             // 262144 bf16 = 524,288 B
  float* yws = (float*)(ws + 34078720);                 // 4*8192*128 f32 = 16,777,216 B
  float* tmax = (float*)(ws + 50855936);                // 1008 f32
  int* dstar = (int*)(ws + 50859968);                   // 1008 i32

  node_argmax_kernel<<<NE * NN, 64, 0, stream>>>(T, tmax, dstar);
  lt_frag_kernel<<<1024, 256, 0, stream>>>(L, Bfrag);
  p_frag_kernel<<<512, 256, 0, stream>>>(x, tmax, dstar, Pfrag);
  gemm_mfma_kernel<<<256, 256, 0, stream>>>(Pfrag, Bfrag, yws);
  sm_kernel<<<2048, 256, 0, stream>>>(yws, out);
}

// Round 5
// 34.960 us; speedup vs baseline: 2.5200x; 1.8453x over previous
//
#include <hip/hip_runtime.h>
#include <hip/hip_bf16.h>
#include <math.h>

#define IN_DIM 512
#define NC 100
#define NN 63
#define NE 16
#define BATCH 8192
#define XP 516   // padded x row stride in floats

typedef __attribute__((ext_vector_type(8))) short bf16x8;
typedef __attribute__((ext_vector_type(4))) float f32x4;

static __device__ __forceinline__ ushort bf16_bits(__hip_bfloat16 h) {
  union { __hip_bfloat16 b; ushort u; } cv; cv.b = h; return cv.u;
}

// ---------------- Kernel A: per-node argmax/max over IN_DIM (verbatim r3) ----------
__global__ __launch_bounds__(64) void node_argmax_kernel(
    const float* __restrict__ T, float* __restrict__ tmax, int* __restrict__ dstar) {
  const int node = blockIdx.x;  // 0..1007 == e*63+n
  const float4* row = reinterpret_cast<const float4*>(T + (size_t)node * IN_DIM);
  const int lane = threadIdx.x;
  float best = -INFINITY;
  int bidx = 0;
#pragma unroll
  for (int i = 0; i < 2; ++i) {
    const int f4 = lane + 64 * i;
    const float4 v = row[f4];
    const int base = f4 * 4;
    if (v.x > best) { best = v.x; bidx = base; }
    if (v.y > best) { best = v.y; bidx = base + 1; }
    if (v.z > best) { best = v.z; bidx = base + 2; }
    if (v.w > best) { best = v.w; bidx = base + 3; }
  }
#pragma unroll
  for (int off = 32; off; off >>= 1) {
    const float ov = __shfl_xor(best, off);
    const int oi = __shfl_xor(bidx, off);
    if (ov > best || (ov == best && oi < bidx)) { best = ov; bidx = oi; }
  }
  if (lane == 0) {
    tmax[node] = best;
    dstar[node] = bidx;
  }
}

// ---------------- Kernel LT: L -> B-fragments [kc][hl][cf][lane][8] (verbatim r3) ---
__global__ __launch_bounds__(256) void lt_frag_kernel(const float* __restrict__ L,
                                                      ushort* __restrict__ Bfrag) {
  const int i = blockIdx.x * 256 + threadIdx.x;  // 262144 elements
  const int j = i & 7;
  const int lane = (i >> 3) & 63;
  const int cf = (i >> 9) & 7;
  const int hl = (i >> 12) & 1;
  const int kc = i >> 13;
  const int k = kc * 32 + (lane >> 4) * 8 + j;
  const int c = cf * 16 + (lane & 15);
  const float val = (c < NC) ? L[(size_t)k * NC + c] : 0.0f;
  const __hip_bfloat16 hb = __float2bfloat16(val);
  ushort outv;
  if (hl == 0) {
    outv = bf16_bits(hb);
  } else {
    const __hip_bfloat16 lb = __float2bfloat16(val - __bfloat162float(hb));
    outv = bf16_bits(lb);
  }
  Bfrag[i] = outv;
}

// ---------------- Kernel F: fused tree-products + MFMA, partials to global ----------
// Block = 16 batch rows. Wave w owns kc = w*8 .. w*8+7; writes k-partial w to yws.
__global__ __launch_bounds__(256) void forest_partial_kernel(
    const float* __restrict__ x, const ushort* __restrict__ Bfrag,
    const float* __restrict__ tmaxg, const int* __restrict__ dstarg,
    float* __restrict__ yws) {
  __shared__ __align__(16) float xl[16 * XP];  // 33024 B
  __shared__ float tl[NE * NN];
  __shared__ int dl[NE * NN];
  const int tid = threadIdx.x;
  const int b0 = blockIdx.x * 16;
  const int w = tid >> 6, lane = tid & 63;

  // ---- stage 16 x rows (f32 exact) + node tables (verbatim r3 p_frag) ----
  {
    const float4* xg = reinterpret_cast<const float4*>(x + (size_t)b0 * IN_DIM);
#pragma unroll
    for (int i = 0; i < 8; ++i) {
      const int idx = tid + i * 256;
      const int r = idx >> 7, c4 = idx & 127;
      *reinterpret_cast<float4*>(&xl[r * XP + c4 * 4]) = xg[r * 128 + c4];
    }
    for (int i = tid; i < NE * NN; i += 256) { tl[i] = tmaxg[i]; dl[i] = dstarg[i]; }
  }
  __syncthreads();

  const int r = lane & 15;
  const int lgq = lane >> 4;
  const float* xr = &xl[r * XP];
  const bf16x8* bf = reinterpret_cast<const bf16x8*>(Bfrag);

  f32x4 acc[8];
#pragma unroll
  for (int cf = 0; cf < 8; ++cf) acc[cf] = (f32x4)0.0f;

  for (int t = 0; t < 8; ++t) {
    const int kc = w * 8 + t;
    const int e = kc >> 1;
    const int lg = (kc & 1) * 4 + lgq;
    const float* te = &tl[e * NN];
    const int* de = &dl[e * NN];

    // path s-values for this thread's 8 leaves (verbatim r3 p_frag math)
    const float s1 = floorf(te[0] - xr[de[0]]);
    const int n2 = 1 + (lg >> 2), n3 = 3 + (lg >> 1), n4 = 7 + lg;
    const float s2 = floorf(te[n2] - xr[de[n2]]);
    const float s3 = floorf(te[n3] - xr[de[n3]]);
    const float s4 = floorf(te[n4] - xr[de[n4]]);
    const int n5 = 15 + 2 * lg, n6 = 31 + 4 * lg;
    const float s5a = floorf(te[n5] - xr[de[n5]]);
    const float s5b = floorf(te[n5 + 1] - xr[de[n5 + 1]]);
    const float s60 = floorf(te[n6] - xr[de[n6]]);
    const float s61 = floorf(te[n6 + 1] - xr[de[n6 + 1]]);
    const float s62 = floorf(te[n6 + 2] - xr[de[n6 + 2]]);
    const float s63 = floorf(te[n6 + 3] - xr[de[n6 + 3]]);

    const float f1 = ((lg >> 2) & 1) ? 1.0f - s1 : s1;
    const float f2 = ((lg >> 1) & 1) ? 1.0f - s2 : s2;
    const float f3 = (lg & 1) ? 1.0f - s3 : s3;
    const float stem = f1 * f2 * f3;
    const float qa = stem * s4, qb = stem * (1.0f - s4);
    const float w00 = qa * s5a, w01 = qa * (1.0f - s5a);
    const float w10 = qb * s5b, w11 = qb * (1.0f - s5b);
    float p[8];
    p[0] = w00 * s60; p[1] = w00 * (1.0f - s60);
    p[2] = w01 * s61; p[3] = w01 * (1.0f - s61);
    p[4] = w10 * s62; p[5] = w10 * (1.0f - s62);
    p[6] = w11 * s63; p[7] = w11 * (1.0f - s63);

    // exact hi/lo bf16 split (verbatim r3 split math)
    union { ushort u[8]; bf16x8 v; } H, Lo;
#pragma unroll
    for (int i2 = 0; i2 < 8; ++i2) {
      const __hip_bfloat16 hb = __float2bfloat16(p[i2]);
      const float hf = __bfloat162float(hb);
      H.u[i2] = bf16_bits(hb);
      Lo.u[i2] = bf16_bits(__float2bfloat16(p[i2] - hf));
    }
    const bf16x8 Ah = H.v, Al = Lo.v;

    // 4-pass MFMA against L2-resident B-fragments (same op order as r3 gemm)
    const size_t bbase = (size_t)kc * 1024;
#pragma unroll
    for (int cf = 0; cf < 8; ++cf) {
      const bf16x8 bh = bf[bbase + (size_t)cf * 64 + lane];
      const bf16x8 bl = bf[bbase + 512 + (size_t)cf * 64 + lane];
      acc[cf] = __builtin_amdgcn_mfma_f32_16x16x32_bf16(Ah, bh, acc[cf], 0, 0, 0);
      acc[cf] = __builtin_amdgcn_mfma_f32_16x16x32_bf16(Al, bh, acc[cf], 0, 0, 0);
      acc[cf] = __builtin_amdgcn_mfma_f32_16x16x32_bf16(Ah, bl, acc[cf], 0, 0, 0);
      acc[cf] = __builtin_amdgcn_mfma_f32_16x16x32_bf16(Al, bl, acc[cf], 0, 0, 0);
    }
  }

  // ---- write k-partial w to global yws[w][row][128] (r3 gemm C/D mapping) ----
  float* yb = yws + (size_t)w * BATCH * 128 + (size_t)b0 * 128;
  const int rlo = (lane >> 4) * 4;
  const int cl = lane & 15;
#pragma unroll
  for (int cf = 0; cf < 8; ++cf)
#pragma unroll
    for (int jj = 0; jj < 4; ++jj)
      yb[(size_t)(rlo + jj) * 128 + cf * 16 + cl] = acc[cf][jj];
}

// ---------------- Kernel S: combine 4 k-partials + masked softmax (verbatim r3) -----
__global__ __launch_bounds__(256) void sm_kernel(const float* __restrict__ yws,
                                                 float* __restrict__ out) {
  const int r = blockIdx.x * 4 + (threadIdx.x >> 6);
  const int lane = threadIdx.x & 63;
  const float* y0 = yws + (size_t)r * 128;
  float v1 = 0.0f, v2 = 0.0f;
#pragma unroll
  for (int s = 0; s < 4; ++s) {
    v1 += y0[(size_t)s * BATCH * 128 + lane];
    v2 += y0[(size_t)s * BATCH * 128 + lane + 64];
  }
  if (lane + 64 >= NC) v2 = -INFINITY;
  float m = fmaxf(v1, v2);
#pragma unroll
  for (int off = 32; off; off >>= 1) m = fmaxf(m, __shfl_xor(m, off));
  const float e1 = __expf(v1 - m);
  const float e2 = (lane + 64 < NC) ? __expf(v2 - m) : 0.0f;
  float ss = e1 + e2;
#pragma unroll
  for (int off = 32; off; off >>= 1) ss += __shfl_xor(ss, off);
  const float inv = 1.0f / ss;
  float* orow = out + (size_t)r * NC;
  orow[lane] = e1 * inv;
  if (lane + 64 < NC) orow[lane + 64] = e2 * inv;
}

extern "C" void kernel_launch(void* const* d_in, const int* in_sizes, int n_in,
                              void* d_out, int out_size, void* d_ws, size_t ws_size,
                              hipStream_t stream) {
  const float* x = (const float*)d_in[0];  // (8192, 512)
  const float* T = (const float*)d_in[1];  // (16, 63, 512)
  const float* L = (const float*)d_in[2];  // (16, 64, 100)
  float* out = (float*)d_out;              // (8192, 100)

  char* ws = (char*)d_ws;
  ushort* Bfrag = (ushort*)ws;              // 262144 bf16 = 524288 B
  float* tmax = (float*)(ws + 524288);      // 1008 f32
  int* dstar = (int*)(ws + 528384);         // 1008 i32
  float* yws = (float*)(ws + 532480);       // 4*8192*128 f32 = 16777216 B

  node_argmax_kernel<<<NE * NN, 64, 0, stream>>>(T, tmax, dstar);
  lt_frag_kernel<<<1024, 256, 0, stream>>>(L, Bfrag);
  forest_partial_kernel<<<BATCH / 16, 256, 0, stream>>>(x, Bfrag, tmax, dstar, yws);
  sm_kernel<<<2048, 256, 0, stream>>>(yws, out);
}

// Round 6
// 26.074 us; speedup vs baseline: 3.3789x; 1.3408x over previous
//
#include <hip/hip_runtime.h>
#include <hip/hip_bf16.h>
#include <math.h>

#define IN_DIM 512
#define NC 100
#define NN 63
#define NE 16
#define BATCH 8192
#define XP 516   // padded x row stride in floats

typedef __attribute__((ext_vector_type(8))) short bf16x8;
typedef __attribute__((ext_vector_type(4))) float f32x4;

static __device__ __forceinline__ ushort bf16_bits(__hip_bfloat16 h) {
  union { __hip_bfloat16 b; ushort u; } cv; cv.b = h; return cv.u;
}

// ---------------- Kernel A: per-node argmax/max over IN_DIM (verbatim r5) ----------
__global__ __launch_bounds__(64) void node_argmax_kernel(
    const float* __restrict__ T, float* __restrict__ tmax, int* __restrict__ dstar) {
  const int node = blockIdx.x;  // 0..1007 == e*63+n
  const float4* row = reinterpret_cast<const float4*>(T + (size_t)node * IN_DIM);
  const int lane = threadIdx.x;
  float best = -INFINITY;
  int bidx = 0;
#pragma unroll
  for (int i = 0; i < 2; ++i) {
    const int f4 = lane + 64 * i;
    const float4 v = row[f4];
    const int base = f4 * 4;
    if (v.x > best) { best = v.x; bidx = base; }
    if (v.y > best) { best = v.y; bidx = base + 1; }
    if (v.z > best) { best = v.z; bidx = base + 2; }
    if (v.w > best) { best = v.w; bidx = base + 3; }
  }
#pragma unroll
  for (int off = 32; off; off >>= 1) {
    const float ov = __shfl_xor(best, off);
    const int oi = __shfl_xor(bidx, off);
    if (ov > best || (ov == best && oi < bidx)) { best = ov; bidx = oi; }
  }
  if (lane == 0) {
    tmax[node] = best;
    dstar[node] = bidx;
  }
}

// ---------------- Kernel LT: L -> B-fragments [kc][hl][cf][lane][8] (verbatim r5) ---
__global__ __launch_bounds__(256) void lt_frag_kernel(const float* __restrict__ L,
                                                      ushort* __restrict__ Bfrag) {
  const int i = blockIdx.x * 256 + threadIdx.x;  // 262144 elements
  const int j = i & 7;
  const int lane = (i >> 3) & 63;
  const int cf = (i >> 9) & 7;
  const int hl = (i >> 12) & 1;
  const int kc = i >> 13;
  const int k = kc * 32 + (lane >> 4) * 8 + j;
  const int c = cf * 16 + (lane & 15);
  const float val = (c < NC) ? L[(size_t)k * NC + c] : 0.0f;
  const __hip_bfloat16 hb = __float2bfloat16(val);
  ushort outv;
  if (hl == 0) {
    outv = bf16_bits(hb);
  } else {
    const __hip_bfloat16 lb = __float2bfloat16(val - __bfloat162float(hb));
    outv = bf16_bits(lb);
  }
  Bfrag[i] = outv;
}

// ---------------- Kernel F: fused tree-products + MFMA + reduce + softmax ----------
// Block = 16 batch rows. Wave w owns kc = w*8 .. w*8+7; partials reduced in LDS.
__global__ __launch_bounds__(256) void forest_fused_kernel(
    const float* __restrict__ x, const ushort* __restrict__ Bfrag,
    const float* __restrict__ tmaxg, const int* __restrict__ dstarg,
    float* __restrict__ out) {
  __shared__ __align__(16) float xl[16 * XP];      // 33024 B
  __shared__ float tl[NE * NN];                    // 4032 B
  __shared__ int dl[NE * NN];                      // 4032 B
  __shared__ __align__(16) float red[4 * 16 * 128];  // 32768 B (separate: no xl alias)
  const int tid = threadIdx.x;
  const int b0 = blockIdx.x * 16;
  const int w = tid >> 6, lane = tid & 63;

  // ---- stage 16 x rows (f32 exact) + node tables (verbatim r5) ----
  {
    const float4* xg = reinterpret_cast<const float4*>(x + (size_t)b0 * IN_DIM);
#pragma unroll
    for (int i = 0; i < 8; ++i) {
      const int idx = tid + i * 256;
      const int r = idx >> 7, c4 = idx & 127;
      *reinterpret_cast<float4*>(&xl[r * XP + c4 * 4]) = xg[r * 128 + c4];
    }
    for (int i = tid; i < NE * NN; i += 256) { tl[i] = tmaxg[i]; dl[i] = dstarg[i]; }
  }
  __syncthreads();

  const int r = lane & 15;
  const int lgq = lane >> 4;
  const float* xr = &xl[r * XP];
  const bf16x8* bf = reinterpret_cast<const bf16x8*>(Bfrag);

  f32x4 acc[8];
#pragma unroll
  for (int cf = 0; cf < 8; ++cf) acc[cf] = (f32x4)0.0f;

  for (int t = 0; t < 8; ++t) {
    const int kc = w * 8 + t;
    const int e = kc >> 1;
    const int lg = (kc & 1) * 4 + lgq;
    const float* te = &tl[e * NN];
    const int* de = &dl[e * NN];

    // path s-values for this thread's 8 leaves (verbatim r5)
    const float s1 = floorf(te[0] - xr[de[0]]);
    const int n2 = 1 + (lg >> 2), n3 = 3 + (lg >> 1), n4 = 7 + lg;
    const float s2 = floorf(te[n2] - xr[de[n2]]);
    const float s3 = floorf(te[n3] - xr[de[n3]]);
    const float s4 = floorf(te[n4] - xr[de[n4]]);
    const int n5 = 15 + 2 * lg, n6 = 31 + 4 * lg;
    const float s5a = floorf(te[n5] - xr[de[n5]]);
    const float s5b = floorf(te[n5 + 1] - xr[de[n5 + 1]]);
    const float s60 = floorf(te[n6] - xr[de[n6]]);
    const float s61 = floorf(te[n6 + 1] - xr[de[n6 + 1]]);
    const float s62 = floorf(te[n6 + 2] - xr[de[n6 + 2]]);
    const float s63 = floorf(te[n6 + 3] - xr[de[n6 + 3]]);

    const float f1 = ((lg >> 2) & 1) ? 1.0f - s1 : s1;
    const float f2 = ((lg >> 1) & 1) ? 1.0f - s2 : s2;
    const float f3 = (lg & 1) ? 1.0f - s3 : s3;
    const float stem = f1 * f2 * f3;
    const float qa = stem * s4, qb = stem * (1.0f - s4);
    const float w00 = qa * s5a, w01 = qa * (1.0f - s5a);
    const float w10 = qb * s5b, w11 = qb * (1.0f - s5b);
    float p[8];
    p[0] = w00 * s60; p[1] = w00 * (1.0f - s60);
    p[2] = w01 * s61; p[3] = w01 * (1.0f - s61);
    p[4] = w10 * s62; p[5] = w10 * (1.0f - s62);
    p[6] = w11 * s63; p[7] = w11 * (1.0f - s63);

    // exact hi/lo bf16 split (verbatim r5)
    union { ushort u[8]; bf16x8 v; } H, Lo;
#pragma unroll
    for (int i2 = 0; i2 < 8; ++i2) {
      const __hip_bfloat16 hb = __float2bfloat16(p[i2]);
      const float hf = __bfloat162float(hb);
      H.u[i2] = bf16_bits(hb);
      Lo.u[i2] = bf16_bits(__float2bfloat16(p[i2] - hf));
    }
    const bf16x8 Ah = H.v, Al = Lo.v;

    // 4-pass MFMA against L2-resident B-fragments (verbatim r5)
    const size_t bbase = (size_t)kc * 1024;
#pragma unroll
    for (int cf = 0; cf < 8; ++cf) {
      const bf16x8 bh = bf[bbase + (size_t)cf * 64 + lane];
      const bf16x8 bl = bf[bbase + 512 + (size_t)cf * 64 + lane];
      acc[cf] = __builtin_amdgcn_mfma_f32_16x16x32_bf16(Ah, bh, acc[cf], 0, 0, 0);
      acc[cf] = __builtin_amdgcn_mfma_f32_16x16x32_bf16(Al, bh, acc[cf], 0, 0, 0);
      acc[cf] = __builtin_amdgcn_mfma_f32_16x16x32_bf16(Ah, bl, acc[cf], 0, 0, 0);
      acc[cf] = __builtin_amdgcn_mfma_f32_16x16x32_bf16(Al, bl, acc[cf], 0, 0, 0);
    }
  }

  // ---- epilogue: k-partial w -> red[w][row][col] (r5 C/D mapping, LDS not global) --
  {
    const int rlo = (lane >> 4) * 4;
    const int cl = lane & 15;
#pragma unroll
    for (int cf = 0; cf < 8; ++cf)
#pragma unroll
      for (int jj = 0; jj < 4; ++jj)
        red[(w * 16 + rlo + jj) * 128 + cf * 16 + cl] = acc[cf][jj];
  }
  __syncthreads();

  // ---- reduce 4 partials + masked softmax + store (same reduce order as r5 sm) ----
  const int rr = tid >> 4;   // row 0..15
  const int cg = tid & 15;   // 8 cols each
  float v[8];
#pragma unroll
  for (int j = 0; j < 8; ++j) {
    const int c = cg * 8 + j;
    v[j] = red[(0 * 16 + rr) * 128 + c] + red[(1 * 16 + rr) * 128 + c] +
           red[(2 * 16 + rr) * 128 + c] + red[(3 * 16 + rr) * 128 + c];
  }
  float m = -INFINITY;
#pragma unroll
  for (int j = 0; j < 8; ++j)
    if (cg * 8 + j < NC) m = fmaxf(m, v[j]);
#pragma unroll
  for (int off = 1; off < 16; off <<= 1) m = fmaxf(m, __shfl_xor(m, off));
  float ev[8];
  float ss = 0.0f;
#pragma unroll
  for (int j = 0; j < 8; ++j) {
    ev[j] = (cg * 8 + j < NC) ? __expf(v[j] - m) : 0.0f;
    ss += ev[j];
  }
#pragma unroll
  for (int off = 1; off < 16; off <<= 1) ss += __shfl_xor(ss, off);
  const float inv = 1.0f / ss;
  float* orow = out + (size_t)(b0 + rr) * NC + cg * 8;
  if (cg < 12) {
    *reinterpret_cast<float4*>(orow) =
        make_float4(ev[0] * inv, ev[1] * inv, ev[2] * inv, ev[3] * inv);
    *reinterpret_cast<float4*>(orow + 4) =
        make_float4(ev[4] * inv, ev[5] * inv, ev[6] * inv, ev[7] * inv);
  } else if (cg == 12) {
    *reinterpret_cast<float4*>(orow) =
        make_float4(ev[0] * inv, ev[1] * inv, ev[2] * inv, ev[3] * inv);
  }
}

extern "C" void kernel_launch(void* const* d_in, const int* in_sizes, int n_in,
                              void* d_out, int out_size, void* d_ws, size_t ws_size,
                              hipStream_t stream) {
  const float* x = (const float*)d_in[0];  // (8192, 512)
  const float* T = (const float*)d_in[1];  // (16, 63, 512)
  const float* L = (const float*)d_in[2];  // (16, 64, 100)
  float* out = (float*)d_out;              // (8192, 100)

  char* ws = (char*)d_ws;
  ushort* Bfrag = (ushort*)ws;              // 262144 bf16 = 524288 B
  float* tmax = (float*)(ws + 524288);      // 1008 f32
  int* dstar = (int*)(ws + 528384);         // 1008 i32

  node_argmax_kernel<<<NE * NN, 64, 0, stream>>>(T, tmax, dstar);
  lt_frag_kernel<<<1024, 256, 0, stream>>>(L, Bfrag);
  forest_fused_kernel<<<BATCH / 16, 256, 0, stream>>>(x, Bfrag, tmax, dstar, out);
}

// Round 7
// 23.981 us; speedup vs baseline: 3.6739x; 1.0873x over previous
//
#include <hip/hip_runtime.h>
#include <hip/hip_bf16.h>
#include <math.h>

#define IN_DIM 512
#define NC 100
#define NN 63
#define NE 16
#define BATCH 8192
#define XP 516   // padded x row stride in floats

typedef __attribute__((ext_vector_type(8))) short bf16x8;
typedef __attribute__((ext_vector_type(4))) float f32x4;

static __device__ __forceinline__ ushort bf16_bits(__hip_bfloat16 h) {
  union { __hip_bfloat16 b; ushort u; } cv; cv.b = h; return cv.u;
}

// ---------------- Kernel 1: fused prep = B-fragments + per-node argmax -------------
// grid 1024 x 256. Every thread writes one Bfrag element (verbatim r6 lt_frag);
// wave 0 of blocks 0..1007 additionally does node argmax (verbatim r6 node_argmax),
// writing SEPARATE tmax/dstar arrays (r6 format, not r4's int2).
__global__ __launch_bounds__(256) void prep_kernel(
    const float* __restrict__ T, const float* __restrict__ L,
    ushort* __restrict__ Bfrag, float* __restrict__ tmax, int* __restrict__ dstar) {
  const int tid = threadIdx.x;
  const int bid = blockIdx.x;

  // --- L -> B-fragments [kc][hl][cf][lane][8] bf16 hi/lo ---
  {
    const int i = bid * 256 + tid;  // 0..262143
    const int j = i & 7;
    const int lane = (i >> 3) & 63;
    const int cf = (i >> 9) & 7;
    const int hl = (i >> 12) & 1;
    const int kc = i >> 13;
    const int k = kc * 32 + (lane >> 4) * 8 + j;
    const int c = cf * 16 + (lane & 15);
    const float val = (c < NC) ? L[(size_t)k * NC + c] : 0.0f;
    const __hip_bfloat16 hb = __float2bfloat16(val);
    ushort outv;
    if (hl == 0) {
      outv = bf16_bits(hb);
    } else {
      const __hip_bfloat16 lb = __float2bfloat16(val - __bfloat162float(hb));
      outv = bf16_bits(lb);
    }
    Bfrag[i] = outv;
  }

  // --- per-node argmax/max over IN_DIM: wave 0 of blocks 0..1007 ---
  if (bid < NE * NN && tid < 64) {
    const float4* row = reinterpret_cast<const float4*>(T + (size_t)bid * IN_DIM);
    const int lane = tid;
    float best = -INFINITY;
    int bidx = 0;
#pragma unroll
    for (int i = 0; i < 2; ++i) {
      const int f4 = lane + 64 * i;
      const float4 v = row[f4];
      const int base = f4 * 4;
      if (v.x > best) { best = v.x; bidx = base; }
      if (v.y > best) { best = v.y; bidx = base + 1; }
      if (v.z > best) { best = v.z; bidx = base + 2; }
      if (v.w > best) { best = v.w; bidx = base + 3; }
    }
#pragma unroll
    for (int off = 32; off; off >>= 1) {
      const float ov = __shfl_xor(best, off);
      const int oi = __shfl_xor(bidx, off);
      if (ov > best || (ov == best && oi < bidx)) { best = ov; bidx = oi; }
    }
    if (lane == 0) {
      tmax[bid] = best;
      dstar[bid] = bidx;
    }
  }
}

// ---------------- Kernel F: fused tree-products + MFMA + reduce + softmax ----------
// Block = 16 batch rows. Wave w owns kc = w*8 .. w*8+7; partials reduced in LDS.
// B loads issued FIRST each t-iteration so A-gen VALU hides L2 latency.
__global__ __launch_bounds__(256, 2) void forest_fused_kernel(
    const float* __restrict__ x, const ushort* __restrict__ Bfrag,
    const float* __restrict__ tmaxg, const int* __restrict__ dstarg,
    float* __restrict__ out) {
  __shared__ __align__(16) float xl[16 * XP];        // 33024 B
  __shared__ float tl[NE * NN];                      // 4032 B
  __shared__ int dl[NE * NN];                        // 4032 B
  __shared__ __align__(16) float red[4 * 16 * 128];  // 32768 B (separate: no xl alias)
  const int tid = threadIdx.x;
  const int b0 = blockIdx.x * 16;
  const int w = tid >> 6, lane = tid & 63;

  // ---- stage 16 x rows (f32 exact) + node tables (verbatim r6) ----
  {
    const float4* xg = reinterpret_cast<const float4*>(x + (size_t)b0 * IN_DIM);
#pragma unroll
    for (int i = 0; i < 8; ++i) {
      const int idx = tid + i * 256;
      const int r = idx >> 7, c4 = idx & 127;
      *reinterpret_cast<float4*>(&xl[r * XP + c4 * 4]) = xg[r * 128 + c4];
    }
    for (int i = tid; i < NE * NN; i += 256) { tl[i] = tmaxg[i]; dl[i] = dstarg[i]; }
  }
  __syncthreads();

  const int r = lane & 15;
  const int lgq = lane >> 4;
  const float* xr = &xl[r * XP];
  const bf16x8* bf = reinterpret_cast<const bf16x8*>(Bfrag);

  f32x4 acc[8];
#pragma unroll
  for (int cf = 0; cf < 8; ++cf) acc[cf] = (f32x4)0.0f;

  for (int t = 0; t < 8; ++t) {
    const int kc = w * 8 + t;
    const int e = kc >> 1;
    const int lg = (kc & 1) * 4 + lgq;

    // ---- issue all 16 B loads up front (L2 latency hides under A-gen below) ----
    const size_t bbase = (size_t)kc * 1024;
    bf16x8 BH[8], BL[8];
#pragma unroll
    for (int cf = 0; cf < 8; ++cf) {
      BH[cf] = bf[bbase + (size_t)cf * 64 + lane];
      BL[cf] = bf[bbase + 512 + (size_t)cf * 64 + lane];
    }

    // ---- A-gen: path s-values for this thread's 8 leaves (verbatim r6) ----
    const float* te = &tl[e * NN];
    const int* de = &dl[e * NN];
    const float s1 = floorf(te[0] - xr[de[0]]);
    const int n2 = 1 + (lg >> 2), n3 = 3 + (lg >> 1), n4 = 7 + lg;
    const float s2 = floorf(te[n2] - xr[de[n2]]);
    const float s3 = floorf(te[n3] - xr[de[n3]]);
    const float s4 = floorf(te[n4] - xr[de[n4]]);
    const int n5 = 15 + 2 * lg, n6 = 31 + 4 * lg;
    const float s5a = floorf(te[n5] - xr[de[n5]]);
    const float s5b = floorf(te[n5 + 1] - xr[de[n5 + 1]]);
    const float s60 = floorf(te[n6] - xr[de[n6]]);
    const float s61 = floorf(te[n6 + 1] - xr[de[n6 + 1]]);
    const float s62 = floorf(te[n6 + 2] - xr[de[n6 + 2]]);
    const float s63 = floorf(te[n6 + 3] - xr[de[n6 + 3]]);

    const float f1 = ((lg >> 2) & 1) ? 1.0f - s1 : s1;
    const float f2 = ((lg >> 1) & 1) ? 1.0f - s2 : s2;
    const float f3 = (lg & 1) ? 1.0f - s3 : s3;
    const float stem = f1 * f2 * f3;
    const float qa = stem * s4, qb = stem * (1.0f - s4);
    const float w00 = qa * s5a, w01 = qa * (1.0f - s5a);
    const float w10 = qb * s5b, w11 = qb * (1.0f - s5b);
    float p[8];
    p[0] = w00 * s60; p[1] = w00 * (1.0f - s60);
    p[2] = w01 * s61; p[3] = w01 * (1.0f - s61);
    p[4] = w10 * s62; p[5] = w10 * (1.0f - s62);
    p[6] = w11 * s63; p[7] = w11 * (1.0f - s63);

    // exact hi/lo bf16 split (verbatim r6)
    union { ushort u[8]; bf16x8 v; } H, Lo;
#pragma unroll
    for (int i2 = 0; i2 < 8; ++i2) {
      const __hip_bfloat16 hb = __float2bfloat16(p[i2]);
      const float hf = __bfloat162float(hb);
      H.u[i2] = bf16_bits(hb);
      Lo.u[i2] = bf16_bits(__float2bfloat16(p[i2] - hf));
    }
    const bf16x8 Ah = H.v, Al = Lo.v;

    // ---- 4-pass MFMA consuming the prefetched B (same op order as r6) ----
#pragma unroll
    for (int cf = 0; cf < 8; ++cf) {
      acc[cf] = __builtin_amdgcn_mfma_f32_16x16x32_bf16(Ah, BH[cf], acc[cf], 0, 0, 0);
      acc[cf] = __builtin_amdgcn_mfma_f32_16x16x32_bf16(Al, BH[cf], acc[cf], 0, 0, 0);
      acc[cf] = __builtin_amdgcn_mfma_f32_16x16x32_bf16(Ah, BL[cf], acc[cf], 0, 0, 0);
      acc[cf] = __builtin_amdgcn_mfma_f32_16x16x32_bf16(Al, BL[cf], acc[cf], 0, 0, 0);
    }
  }

  // ---- epilogue: k-partial w -> red[w][row][col] (verbatim r6) ----
  {
    const int rlo = (lane >> 4) * 4;
    const int cl = lane & 15;
#pragma unroll
    for (int cf = 0; cf < 8; ++cf)
#pragma unroll
      for (int jj = 0; jj < 4; ++jj)
        red[(w * 16 + rlo + jj) * 128 + cf * 16 + cl] = acc[cf][jj];
  }
  __syncthreads();

  // ---- reduce 4 partials + masked softmax + store (verbatim r6) ----
  const int rr = tid >> 4;   // row 0..15
  const int cg = tid & 15;   // 8 cols each
  float v[8];
#pragma unroll
  for (int j = 0; j < 8; ++j) {
    const int c = cg * 8 + j;
    v[j] = red[(0 * 16 + rr) * 128 + c] + red[(1 * 16 + rr) * 128 + c] +
           red[(2 * 16 + rr) * 128 + c] + red[(3 * 16 + rr) * 128 + c];
  }
  float m = -INFINITY;
#pragma unroll
  for (int j = 0; j < 8; ++j)
    if (cg * 8 + j < NC) m = fmaxf(m, v[j]);
#pragma unroll
  for (int off = 1; off < 16; off <<= 1) m = fmaxf(m, __shfl_xor(m, off));
  float ev[8];
  float ss = 0.0f;
#pragma unroll
  for (int j = 0; j < 8; ++j) {
    ev[j] = (cg * 8 + j < NC) ? __expf(v[j] - m) : 0.0f;
    ss += ev[j];
  }
#pragma unroll
  for (int off = 1; off < 16; off <<= 1) ss += __shfl_xor(ss, off);
  const float inv = 1.0f / ss;
  float* orow = out + (size_t)(b0 + rr) * NC + cg * 8;
  if (cg < 12) {
    *reinterpret_cast<float4*>(orow) =
        make_float4(ev[0] * inv, ev[1] * inv, ev[2] * inv, ev[3] * inv);
    *reinterpret_cast<float4*>(orow + 4) =
        make_float4(ev[4] * inv, ev[5] * inv, ev[6] * inv, ev[7] * inv);
  } else if (cg == 12) {
    *reinterpret_cast<float4*>(orow) =
        make_float4(ev[0] * inv, ev[1] * inv, ev[2] * inv, ev[3] * inv);
  }
}

extern "C" void kernel_launch(void* const* d_in, const int* in_sizes, int n_in,
                              void* d_out, int out_size, void* d_ws, size_t ws_size,
                              hipStream_t stream) {
  const float* x = (const float*)d_in[0];  // (8192, 512)
  const float* T = (const float*)d_in[1];  // (16, 63, 512)
  const float* L = (const float*)d_in[2];  // (16, 64, 100)
  float* out = (float*)d_out;              // (8192, 100)

  char* ws = (char*)d_ws;
  ushort* Bfrag = (ushort*)ws;              // 262144 bf16 = 524288 B
  float* tmax = (float*)(ws + 524288);      // 1008 f32
  int* dstar = (int*)(ws + 528384);         // 1008 i32

  prep_kernel<<<1024, 256, 0, stream>>>(T, L, Bfrag, tmax, dstar);
  forest_fused_kernel<<<BATCH / 16, 256, 0, stream>>>(x, Bfrag, tmax, dstar, out);
}

// Round 8
// 22.137 us; speedup vs baseline: 3.9799x; 1.0833x over previous
//
#include <hip/hip_runtime.h>
#include <hip/hip_bf16.h>
#include <math.h>

#define IN_DIM 512
#define NC 100
#define NN 63
#define NE 16
#define BATCH 8192
#define XP 516   // padded x row stride in floats (516 mod 32 = 4 -> 2-way-free gathers)

typedef __attribute__((ext_vector_type(8))) short bf16x8;
typedef __attribute__((ext_vector_type(4))) float f32x4;

static __device__ __forceinline__ ushort bf16_bits(__hip_bfloat16 h) {
  union { __hip_bfloat16 b; ushort u; } cv; cv.b = h; return cv.u;
}

// ---------------- Kernel 1: fused prep = B-fragments + per-node argmax (verbatim r7)
__global__ __launch_bounds__(256) void prep_kernel(
    const float* __restrict__ T, const float* __restrict__ L,
    ushort* __restrict__ Bfrag, float* __restrict__ tmax, int* __restrict__ dstar) {
  const int tid = threadIdx.x;
  const int bid = blockIdx.x;

  // --- L -> B-fragments [kc][hl][cf][lane][8] bf16 hi/lo ---
  {
    const int i = bid * 256 + tid;  // 0..262143
    const int j = i & 7;
    const int lane = (i >> 3) & 63;
    const int cf = (i >> 9) & 7;
    const int hl = (i >> 12) & 1;
    const int kc = i >> 13;
    const int k = kc * 32 + (lane >> 4) * 8 + j;
    const int c = cf * 16 + (lane & 15);
    const float val = (c < NC) ? L[(size_t)k * NC + c] : 0.0f;
    const __hip_bfloat16 hb = __float2bfloat16(val);
    ushort outv;
    if (hl == 0) {
      outv = bf16_bits(hb);
    } else {
      const __hip_bfloat16 lb = __float2bfloat16(val - __bfloat162float(hb));
      outv = bf16_bits(lb);
    }
    Bfrag[i] = outv;
  }

  // --- per-node argmax/max over IN_DIM: wave 0 of blocks 0..1007 ---
  if (bid < NE * NN && tid < 64) {
    const float4* row = reinterpret_cast<const float4*>(T + (size_t)bid * IN_DIM);
    const int lane = tid;
    float best = -INFINITY;
    int bidx = 0;
#pragma unroll
    for (int i = 0; i < 2; ++i) {
      const int f4 = lane + 64 * i;
      const float4 v = row[f4];
      const int base = f4 * 4;
      if (v.x > best) { best = v.x; bidx = base; }
      if (v.y > best) { best = v.y; bidx = base + 1; }
      if (v.z > best) { best = v.z; bidx = base + 2; }
      if (v.w > best) { best = v.w; bidx = base + 3; }
    }
#pragma unroll
    for (int off = 32; off; off >>= 1) {
      const float ov = __shfl_xor(best, off);
      const int oi = __shfl_xor(bidx, off);
      if (ov > best || (ov == best && oi < bidx)) { best = ov; bidx = oi; }
    }
    if (lane == 0) {
      tmax[bid] = best;
      dstar[bid] = bidx;
    }
  }
}

// ---------------- Kernel F: 32 rows/block, 8 waves; wave = 4 kc x 2 row-tiles -------
__global__ __launch_bounds__(512, 2) void forest_fused_kernel(
    const float* __restrict__ x, const ushort* __restrict__ Bfrag,
    const float* __restrict__ tmaxg, const int* __restrict__ dstarg,
    float* __restrict__ out) {
  __shared__ __align__(16) float xl[32 * XP];          // 66048 B
  __shared__ float tl[NE * NN];                        // 4032 B
  __shared__ int dl[NE * NN];                          // 4032 B
  __shared__ __align__(16) float red[8 * 16 * 128];    // 65536 B (no xl alias!)
  const int tid = threadIdx.x;
  const int b0 = blockIdx.x * 32;
  const int w = tid >> 6, lane = tid & 63;

  // ---- stage 32 x rows (f32 exact) + node tables ----
  {
    const float4* xg = reinterpret_cast<const float4*>(x + (size_t)b0 * IN_DIM);
#pragma unroll
    for (int i = 0; i < 8; ++i) {
      const int idx = tid + i * 512;    // 0..4095
      const int r = idx >> 7, c4 = idx & 127;
      *reinterpret_cast<float4*>(&xl[r * XP + c4 * 4]) = xg[r * 128 + c4];
    }
    for (int i = tid; i < NE * NN; i += 512) { tl[i] = tmaxg[i]; dl[i] = dstarg[i]; }
  }
  __syncthreads();

  const int r = lane & 15;
  const int lgq = lane >> 4;
  const float* xr0 = &xl[r * XP];
  const float* xr1 = &xl[(r + 16) * XP];
  const bf16x8* bf = reinterpret_cast<const bf16x8*>(Bfrag);

  // A-gen: verbatim r7 math, parameterized by x-row pointer
  auto agen = [&](const float* xr, int lg, const float* te, const int* de,
                  bf16x8& Ah, bf16x8& Al) {
    const float s1 = floorf(te[0] - xr[de[0]]);
    const int n2 = 1 + (lg >> 2), n3 = 3 + (lg >> 1), n4 = 7 + lg;
    const float s2 = floorf(te[n2] - xr[de[n2]]);
    const float s3 = floorf(te[n3] - xr[de[n3]]);
    const float s4 = floorf(te[n4] - xr[de[n4]]);
    const int n5 = 15 + 2 * lg, n6 = 31 + 4 * lg;
    const float s5a = floorf(te[n5] - xr[de[n5]]);
    const float s5b = floorf(te[n5 + 1] - xr[de[n5 + 1]]);
    const float s60 = floorf(te[n6] - xr[de[n6]]);
    const float s61 = floorf(te[n6 + 1] - xr[de[n6 + 1]]);
    const float s62 = floorf(te[n6 + 2] - xr[de[n6 + 2]]);
    const float s63 = floorf(te[n6 + 3] - xr[de[n6 + 3]]);
    const float f1 = ((lg >> 2) & 1) ? 1.0f - s1 : s1;
    const float f2 = ((lg >> 1) & 1) ? 1.0f - s2 : s2;
    const float f3 = (lg & 1) ? 1.0f - s3 : s3;
    const float stem = f1 * f2 * f3;
    const float qa = stem * s4, qb = stem * (1.0f - s4);
    const float w00 = qa * s5a, w01 = qa * (1.0f - s5a);
    const float w10 = qb * s5b, w11 = qb * (1.0f - s5b);
    float p[8];
    p[0] = w00 * s60; p[1] = w00 * (1.0f - s60);
    p[2] = w01 * s61; p[3] = w01 * (1.0f - s61);
    p[4] = w10 * s62; p[5] = w10 * (1.0f - s62);
    p[6] = w11 * s63; p[7] = w11 * (1.0f - s63);
    union { ushort u[8]; bf16x8 v; } H, Lo;
#pragma unroll
    for (int i2 = 0; i2 < 8; ++i2) {
      const __hip_bfloat16 hb = __float2bfloat16(p[i2]);
      const float hf = __bfloat162float(hb);
      H.u[i2] = bf16_bits(hb);
      Lo.u[i2] = bf16_bits(__float2bfloat16(p[i2] - hf));
    }
    Ah = H.v; Al = Lo.v;
  };

  f32x4 acc0[8], acc1[8];
#pragma unroll
  for (int cf = 0; cf < 8; ++cf) { acc0[cf] = (f32x4)0.0f; acc1[cf] = (f32x4)0.0f; }

  for (int t = 0; t < 4; ++t) {
    const int kc = w * 4 + t;
    const int e = kc >> 1;
    const int lg = (kc & 1) * 4 + lgq;

    // ---- issue 16 B loads up front; A-gen x2 hides L2 latency ----
    const size_t bbase = (size_t)kc * 1024;
    bf16x8 BH[8], BL[8];
#pragma unroll
    for (int cf = 0; cf < 8; ++cf) {
      BH[cf] = bf[bbase + (size_t)cf * 64 + lane];
      BL[cf] = bf[bbase + 512 + (size_t)cf * 64 + lane];
    }

    const float* te = &tl[e * NN];
    const int* de = &dl[e * NN];
    bf16x8 Ah, Al;

    agen(xr0, lg, te, de, Ah, Al);
#pragma unroll
    for (int cf = 0; cf < 8; ++cf) {
      acc0[cf] = __builtin_amdgcn_mfma_f32_16x16x32_bf16(Ah, BH[cf], acc0[cf], 0, 0, 0);
      acc0[cf] = __builtin_amdgcn_mfma_f32_16x16x32_bf16(Al, BH[cf], acc0[cf], 0, 0, 0);
      acc0[cf] = __builtin_amdgcn_mfma_f32_16x16x32_bf16(Ah, BL[cf], acc0[cf], 0, 0, 0);
      acc0[cf] = __builtin_amdgcn_mfma_f32_16x16x32_bf16(Al, BL[cf], acc0[cf], 0, 0, 0);
    }
    agen(xr1, lg, te, de, Ah, Al);
#pragma unroll
    for (int cf = 0; cf < 8; ++cf) {
      acc1[cf] = __builtin_amdgcn_mfma_f32_16x16x32_bf16(Ah, BH[cf], acc1[cf], 0, 0, 0);
      acc1[cf] = __builtin_amdgcn_mfma_f32_16x16x32_bf16(Al, BH[cf], acc1[cf], 0, 0, 0);
      acc1[cf] = __builtin_amdgcn_mfma_f32_16x16x32_bf16(Ah, BL[cf], acc1[cf], 0, 0, 0);
      acc1[cf] = __builtin_amdgcn_mfma_f32_16x16x32_bf16(Al, BL[cf], acc1[cf], 0, 0, 0);
    }
  }

  // ---- epilogue: two passes (rows 0-15, then 16-31) through one 64 KB red buffer ---
  const int rlo = (lane >> 4) * 4;
  const int cl = lane & 15;
  const int rr = tid >> 5;   // 0..15
  const int cg = tid & 31;   // 4 cols each

  auto epi = [&](const f32x4 (&ac)[8], int rowbase) {
#pragma unroll
    for (int cf = 0; cf < 8; ++cf)
#pragma unroll
      for (int jj = 0; jj < 4; ++jj)
        red[(w * 16 + rlo + jj) * 128 + cf * 16 + cl] = ac[cf][jj];
    __syncthreads();
    float v[4];
#pragma unroll
    for (int j = 0; j < 4; ++j) {
      const int c = cg * 4 + j;
      float s = red[(0 * 16 + rr) * 128 + c];
#pragma unroll
      for (int pw = 1; pw < 8; ++pw) s += red[(pw * 16 + rr) * 128 + c];
      v[j] = s;
    }
    float m = -INFINITY;
#pragma unroll
    for (int j = 0; j < 4; ++j)
      if (cg * 4 + j < NC) m = fmaxf(m, v[j]);
#pragma unroll
    for (int off = 1; off < 32; off <<= 1) m = fmaxf(m, __shfl_xor(m, off));
    float ev[4];
    float ss = 0.0f;
#pragma unroll
    for (int j = 0; j < 4; ++j) {
      ev[j] = (cg * 4 + j < NC) ? __expf(v[j] - m) : 0.0f;
      ss += ev[j];
    }
#pragma unroll
    for (int off = 1; off < 32; off <<= 1) ss += __shfl_xor(ss, off);
    const float inv = 1.0f / ss;
    if (cg < 25) {
      float* orow = out + (size_t)(b0 + rowbase + rr) * NC + cg * 4;
      *reinterpret_cast<float4*>(orow) =
          make_float4(ev[0] * inv, ev[1] * inv, ev[2] * inv, ev[3] * inv);
    }
  };

  epi(acc0, 0);
  __syncthreads();   // pass-0 reads done before pass-1 overwrites red
  epi(acc1, 16);
}

extern "C" void kernel_launch(void* const* d_in, const int* in_sizes, int n_in,
                              void* d_out, int out_size, void* d_ws, size_t ws_size,
                              hipStream_t stream) {
  const float* x = (const float*)d_in[0];  // (8192, 512)
  const float* T = (const float*)d_in[1];  // (16, 63, 512)
  const float* L = (const float*)d_in[2];  // (16, 64, 100)
  float* out = (float*)d_out;              // (8192, 100)

  char* ws = (char*)d_ws;
  ushort* Bfrag = (ushort*)ws;              // 262144 bf16 = 524288 B
  float* tmax = (float*)(ws + 524288);      // 1008 f32
  int* dstar = (int*)(ws + 528384);         // 1008 i32

  prep_kernel<<<1024, 256, 0, stream>>>(T, L, Bfrag, tmax, dstar);
  forest_fused_kernel<<<BATCH / 32, 512, 0, stream>>>(x, Bfrag, tmax, dstar, out);
}